// Round 1
// 614.989 us; speedup vs baseline: 1.1048x; 1.1048x over previous
//
#include <hip/hip_runtime.h>
#include <math.h>

#define EPSV 1e-5f
#define HD 128
#define IT 64
#define JT 32
#define WP 68
#define CCH 16
#define THR 256

typedef __attribute__((address_space(3))) uint32_t lds_u32_t;
typedef __attribute__((address_space(1))) uint32_t gbl_u32_t;
typedef __attribute__((ext_vector_type(8))) short bf16x8;
typedef __attribute__((ext_vector_type(4))) float f32x4;

__device__ __forceinline__ void async_copy16(const float* g, float* l) {
    __builtin_amdgcn_global_load_lds((const gbl_u32_t*)g, (lds_u32_t*)l, 16, 0, 0);
}

// stage a JT x HD fp32 tile (16 KB) global -> LDS via async DMA (256 threads)
__device__ __forceinline__ void stage_tile_async(const float* gsrc, float* lds, int t) {
    int wv = t >> 6, lane = t & 63;
#pragma unroll
    for (int it = 0; it < 4; ++it) {
        int c = it * 4 + wv;
        async_copy16(gsrc + c * 256 + lane * 4, lds + c * 256);
    }
}

// stage an 8 KB bf16 tile global -> LDS via async DMA (256 threads, 2 insts)
__device__ __forceinline__ void stage_8k(const void* g, void* l, int t) {
    const float* gf = (const float*)g; float* lf = (float*)l;
    async_copy16(gf + t * 4, lf + t * 4);
    async_copy16(gf + t * 4 + 1024, lf + t * 4 + 1024);
}

__device__ __forceinline__ unsigned int f2bf(float f) {
    return __builtin_bit_cast(unsigned int, f) >> 16;
}

// round-to-nearest-even fp32 -> bf16
__device__ __forceinline__ unsigned short rne_bf16(float f) {
    unsigned int u = __builtin_bit_cast(unsigned int, f);
    u += 0x7FFFu + ((u >> 16) & 1u);
    return (unsigned short)(u >> 16);
}

// ---------------- param structs ----------------
struct WprepP { const float *W, *a1, *a2; unsigned short* WT; float *wa1, *wa2; int K; };
struct XprepP { const float* X; unsigned short* Xbf; const float *wa1, *wa2;
                float *sa, *sb; int rows; };
struct GmfP   { const unsigned short *Xbf, *WT; unsigned short* hT; int N, tilesJ; };
struct AggP  { const float *adj, *sa, *sb, *sm; const unsigned short* hT;
               float *pp, *zp; int N, tiles, tilesJ, tps; };
struct CrossP{ const float *A, *src, *rs1; float *pp; int iN, jN, tiles, tps; };
struct FinP  { const float *pp, *zp; float *out; int rows, S; };
struct MlpP  { const float *pp, *scale; int S; const float *W1, *b1, *W2, *b2, *res;
               float *out; int rows; };

// ---------------- normalization scale kernels ----------------

__global__ void colsum_part_k(const float* __restrict__ A, float* __restrict__ s1p,
                              int B, int NO, int NV) {
    int v = blockIdx.x * 256 + threadIdx.x;
    int c = blockIdx.y, b = blockIdx.z;
    if (v >= NV) return;
    int chunk = (NO + CCH - 1) / CCH;
    int o0 = c * chunk;
    int o1 = o0 + chunk; if (o1 > NO) o1 = NO;
    const float* Ab = A + (size_t)b * NO * NV + v;
    float s = 0.f;
    for (int o = o0; o < o1; ++o) s += Ab[(size_t)o * NV];
    s1p[((size_t)b * CCH + c) * NV + v] = s;
}

__global__ void colsum_fin_k(const float* __restrict__ s1p, float* __restrict__ rs1,
                             int B, int NV) {
    int idx = blockIdx.x * 256 + threadIdx.x;
    if (idx >= B * NV) return;
    int b = idx / NV, v = idx - b * NV;
    float s = 0.f;
    for (int c = 0; c < CCH; ++c) s += s1p[((size_t)b * CCH + c) * NV + v];
    rs1[idx] = 1.f / (s + EPSV);
}

__global__ void rowsum_inv_k(const float* __restrict__ A, const float* __restrict__ rs1,
                             float* __restrict__ rs2, int B, int NO, int NV) {
    int row = blockIdx.x * (blockDim.x >> 6) + (threadIdx.x >> 6);
    int lane = threadIdx.x & 63;
    if (row >= B * NO) return;
    int b = row / NO;
    const float* Ar = A + (size_t)row * NV;
    const float* r1 = rs1 + (size_t)b * NV;
    float s = 0.f;
    for (int v = lane; v < NV; v += 64) s += Ar[v] * r1[v];
    for (int off = 32; off; off >>= 1) s += __shfl_xor(s, off, 64);
    if (lane == 0) rs2[row] = 1.f / (s + EPSV);
}

// ---------------- weight prep (runs once): WT[c][k] bf16 + wa1/wa2 = W @ a ----------
__global__ __launch_bounds__(256)
void wprep_k(WprepP p0, WprepP p1, WprepP p2, WprepP p3, int e0, int e1, int e2) {
    __shared__ float lw[32][129];
    __shared__ float a1s[128], a2s[128];
    int bid = blockIdx.x;
    const WprepP& P = bid < e0 ? p0 : bid < e1 ? p1 : bid < e2 ? p2 : p3;
    int lb = bid < e0 ? bid : bid < e1 ? bid - e0 : bid < e2 ? bid - e1 : bid - e2;
    int k0 = lb * 32, K = P.K;
    int t = threadIdx.x;
    if (t < 128) { a1s[t] = P.a1[t]; a2s[t] = P.a2[t]; }
    for (int idx = t; idx < 32 * 32; idx += 256) {   // float4 granularity
        int kk = idx >> 5, c4 = idx & 31;
        float4 v = ((const float4*)(P.W + (size_t)(k0 + kk) * 128))[c4];
        lw[kk][c4 * 4 + 0] = v.x; lw[kk][c4 * 4 + 1] = v.y;
        lw[kk][c4 * 4 + 2] = v.z; lw[kk][c4 * 4 + 3] = v.w;
    }
    __syncthreads();
    // wa1/wa2: 8 lanes per k-row
    int kk = t >> 3, g = t & 7;
    float s1 = 0.f, s2 = 0.f;
    for (int c = g; c < 128; c += 8) {
        float w = lw[kk][c];
        s1 = fmaf(w, a1s[c], s1);
        s2 = fmaf(w, a2s[c], s2);
    }
    s1 += __shfl_xor(s1, 1, 64); s1 += __shfl_xor(s1, 2, 64); s1 += __shfl_xor(s1, 4, 64);
    s2 += __shfl_xor(s2, 1, 64); s2 += __shfl_xor(s2, 2, 64); s2 += __shfl_xor(s2, 4, 64);
    if (g == 0) { P.wa1[k0 + kk] = s1; P.wa2[k0 + kk] = s2; }
    // transposed bf16 store: WT[c][k]
    for (int idx = t; idx < 4096; idx += 256) {
        int c = idx >> 5, k = idx & 31;
        P.WT[(size_t)c * K + k0 + k] = rne_bf16(lw[k][c]);
    }
}

// ---------------- X prep: Xbf = rne_bf16(X); sa = X.wa1, sb = X.wa2 (exact fp32) ----
template<int K>
__device__ void xprep_body(const XprepP& P, int lb) {
    int t = threadIdx.x, wv = t >> 6, lane = t & 63;
    int row = lb * 4 + wv;
    if (row >= P.rows) return;
    const float4* x4 = (const float4*)(P.X + (size_t)row * K);
    const float4* w14 = (const float4*)P.wa1;
    const float4* w24 = (const float4*)P.wa2;
    unsigned short* xb = P.Xbf + (size_t)row * K;
    float s1 = 0.f, s2 = 0.f;
    constexpr int K4 = K / 4;
    constexpr int NI = (K4 + 63) / 64;
#pragma unroll
    for (int i = 0; i < NI; ++i) {
        int k4 = i * 64 + lane;
        if ((K4 % 64 == 0) || (k4 < K4)) {
            float4 x = x4[k4];
            float4 a = w14[k4];
            float4 b = w24[k4];
            s1 += x.x * a.x + x.y * a.y + x.z * a.z + x.w * a.w;
            s2 += x.x * b.x + x.y * b.y + x.z * b.z + x.w * b.w;
            ushort4 p = make_ushort4(rne_bf16(x.x), rne_bf16(x.y),
                                     rne_bf16(x.z), rne_bf16(x.w));
            *(ushort4*)(xb + (size_t)k4 * 4) = p;
        }
    }
#pragma unroll
    for (int off = 32; off; off >>= 1) {
        s1 += __shfl_xor(s1, off, 64);
        s2 += __shfl_xor(s2, off, 64);
    }
    if (lane == 0) { P.sa[row] = s1; P.sb[row] = s2; }
}

template<int KV, int KO>
__global__ __launch_bounds__(256)
void xprep2_k(XprepP V, XprepP O, int GV) {
    int bid = blockIdx.x;
    if (bid < GV) xprep_body<KV>(V, bid);
    else          xprep_body<KO>(O, bid - GV);
}

// ---------------- MFMA h-GEMM producing hT directly ----------------
// D[m=c][n=jl] = sum_k WT[c][k] * Xbf[row0+jl][k]  via mfma_f32_16x16x32_bf16.
// A-frag: A[m=lane&15][k=quad*8+i]; B-frag: B[k=quad*8+i][n=lane&15];
// C/D: col=lane&15 (jl), row=quad*4+reg (c)  — same conventions as agg2_k (verified).
template<int K>
__device__ void gmf_body(const GmfP& P, int lb) {
    int tilesJ = P.tilesJ, N = P.N;
    int b = lb / tilesJ, jt = lb - b * tilesJ;
    int t = threadIdx.x, wv = t >> 6, lane = t & 63;
    int ml = lane & 15, quad = lane >> 4;
    const unsigned short* xb = P.Xbf + ((size_t)b * N + (size_t)jt * 32) * K;
    const unsigned short* wt0 = P.WT + (size_t)(wv * 32 + ml) * K;
    const unsigned short* wt1 = wt0 + (size_t)16 * K;
    const unsigned short* xb0 = xb + (size_t)ml * K;
    const unsigned short* xb1 = xb + (size_t)(16 + ml) * K;
    f32x4 acc00 = {0.f, 0.f, 0.f, 0.f}, acc01 = acc00, acc10 = acc00, acc11 = acc00;
#pragma unroll 4
    for (int kt = 0; kt < K / 32; ++kt) {
        int kk = kt * 32 + quad * 8;
        bf16x8 a0 = *(const bf16x8*)(wt0 + kk);
        bf16x8 a1 = *(const bf16x8*)(wt1 + kk);
        bf16x8 b0 = *(const bf16x8*)(xb0 + kk);
        bf16x8 b1 = *(const bf16x8*)(xb1 + kk);
        acc00 = __builtin_amdgcn_mfma_f32_16x16x32_bf16(a0, b0, acc00, 0, 0, 0);
        acc01 = __builtin_amdgcn_mfma_f32_16x16x32_bf16(a0, b1, acc01, 0, 0, 0);
        acc10 = __builtin_amdgcn_mfma_f32_16x16x32_bf16(a1, b0, acc10, 0, 0, 0);
        acc11 = __builtin_amdgcn_mfma_f32_16x16x32_bf16(a1, b1, acc11, 0, 0, 0);
    }
    unsigned short* hb = P.hT + (size_t)(b * tilesJ + jt) * 4096;
    int nvalid = N - jt * 32; if (nvalid > 32) nvalid = 32;
    bool ok0 = ml < nvalid, ok1 = (16 + ml) < nvalid;
    int c0 = wv * 32 + quad * 4;
#pragma unroll
    for (int r = 0; r < 4; ++r) {
        hb[(size_t)(c0 + r) * 32 + ml]           = ok0 ? rne_bf16(acc00[r]) : 0;
        hb[(size_t)(c0 + r) * 32 + 16 + ml]      = ok1 ? rne_bf16(acc01[r]) : 0;
        hb[(size_t)(c0 + 16 + r) * 32 + ml]      = ok0 ? rne_bf16(acc10[r]) : 0;
        hb[(size_t)(c0 + 16 + r) * 32 + 16 + ml] = ok1 ? rne_bf16(acc11[r]) : 0;
    }
}

template<int KV, int KO>
__global__ __launch_bounds__(256)
void gmf2_k(GmfP V, GmfP O, int GV) {
    int bid = blockIdx.x;
    if (bid < GV) gmf_body<KV>(V, bid);
    else          gmf_body<KO>(O, bid - GV);
}

// ---------------- fused per-batch sb max ----------------
__global__ __launch_bounds__(256)
void sbmax2_k(const float* __restrict__ sbV, float* __restrict__ smV,
              const float* __restrict__ sbO, float* __restrict__ smO,
              int NV, int NO) {
    __shared__ float red[256];
    int b0 = blockIdx.x, t = threadIdx.x;
    const float* sb; float* out; int N;
    if (b0 < 8) { sb = sbV + (size_t)b0 * NV; out = smV + b0; N = NV; }
    else        { sb = sbO + (size_t)(b0 - 8) * NO; out = smO + (b0 - 8); N = NO; }
    float m = -INFINITY;
    for (int j = t; j < N; j += 256) m = fmaxf(m, sb[j]);
    red[t] = m; __syncthreads();
    for (int s = 128; s; s >>= 1) {
        if (t < s) red[t] = fmaxf(red[t], red[t + s]);
        __syncthreads();
    }
    if (t == 0) *out = red[0];
}

// ---------------- MFMA GAT aggregation (vis+obj fused) ----------------
// out[IT x HD] += P[IT x JT] @ H[JT x HD] per K-tile via mfma_f32_16x16x32_bf16.
// A-frag: A[m=lane&15][k=quad*8+i] (m120-verified); B-frag: B[k=quad*8+i][n=lane&15];
// C/D: col=lane&15, row=quad*4+reg (m89-verified).
struct SharedAggM {
    unsigned short hsT[2][128][32];    // [c][jl] bf16, DMA'd from hT
    unsigned short wsA[2][4][64][8];   // A-fragment order per wave
    float sa_s[IT], m_s[IT];
};

__device__ void agg_body(SharedAggM& sm, const AggP& P, int lbid) {
    int tiles = P.tiles;
    int split = lbid / (8 * tiles);
    int rem = lbid - split * 8 * tiles;
    int b = rem / tiles;
    int i0 = (rem - b * tiles) * IT;
    int N = P.N;
    int jt0 = split * P.tps;
    if (jt0 >= P.tilesJ) return;
    int jt1 = jt0 + P.tps; if (jt1 > P.tilesJ) jt1 = P.tilesJ;
    int T = jt1 - jt0;
    int t = threadIdx.x;
    if (t < IT) {
        int i = i0 + t;
        float s = (i < N) ? P.sa[(size_t)b * N + i] : 0.f;
        sm.sa_s[t] = s;
        float e = s + P.sm[b];
        sm.m_s[t] = e > 0.f ? e : 0.2f * e;
    }
    __syncthreads();
    int wv = t >> 6, lane = t & 63;
    // w-producer role: thread owns row il, j-offsets {j4..j4+3, j4+16..j4+19}
    int il = t >> 2, j4 = (t & 3) * 4;
    int q0 = j4 >> 3, i0w = j4 & 7, wrow = il & 15;
    // MFMA consumer role
    int nquad = lane >> 4, nlow = lane & 15;
    f32x4 acc[8];
#pragma unroll
    for (int nt = 0; nt < 8; ++nt)
#pragma unroll
        for (int r = 0; r < 4; ++r) acc[nt][r] = 0.f;
    float zacc = 0.f;
    const float* adjb = P.adj + ((size_t)b * N + i0) * N;
    const float* sbb = P.sb + (size_t)b * N;
    const unsigned short* hTb = P.hT + ((size_t)b * P.tilesJ + jt0) * 4096;
    int irow = i0 + il;
    // prologue: DMA tile0 + adj regs tile0
    stage_8k(hTb, &sm.hsT[0][0][0], t);
    float4 a4[2], s4[2];
#pragma unroll
    for (int k = 0; k < 2; ++k) {
        int j = jt0 * JT + j4 + k * 16;
        float4 av = make_float4(0.f,0.f,0.f,0.f), sv = make_float4(0.f,0.f,0.f,0.f);
        if (irow < N) {
            if (j + 3 < N) {
                av = *(const float4*)&adjb[(size_t)il * N + j];
                sv = *(const float4*)&sbb[j];
            } else {
                float* ap = (float*)&av; float* sp = (float*)&sv;
                for (int r = 0; r < 4; ++r)
                    if (j + r < N) { ap[r] = adjb[(size_t)il * N + j + r]; sp[r] = sbb[j + r]; }
            }
        }
        a4[k] = av; s4[k] = sv;
    }
    for (int tt = 0; tt < T; ++tt) {
        int cur = tt & 1;
        float sai = sm.sa_s[il], m = sm.m_s[il];
#pragma unroll
        for (int k = 0; k < 2; ++k) {
            float av[4] = {a4[k].x, a4[k].y, a4[k].z, a4[k].w};
            float sv[4] = {s4[k].x, s4[k].y, s4[k].z, s4[k].w};
            float w[4];
#pragma unroll
            for (int r = 0; r < 4; ++r) {
                float e = sai + sv[r];
                e = e > 0.f ? e : 0.2f * e;
                w[r] = av[r] > 0.f ? __expf(e - m) : 0.f;
                zacc += w[r];
            }
            unsigned int lo = f2bf(w[0]) | (__builtin_bit_cast(unsigned int, w[1]) & 0xFFFF0000u);
            unsigned int hi = f2bf(w[2]) | (__builtin_bit_cast(unsigned int, w[3]) & 0xFFFF0000u);
            uint2 pk = make_uint2(lo, hi);
            *(uint2*)&sm.wsA[cur][wv][wrow + 16 * (q0 + 2 * k)][i0w] = pk;
        }
        __syncthreads();   // wsA[cur] visible; hsT[cur] DMA drained
        if (tt + 1 < T) {
            stage_8k(hTb + (size_t)(tt + 1) * 4096, &sm.hsT[1 - cur][0][0], t);
#pragma unroll
            for (int k = 0; k < 2; ++k) {
                int j = (jt0 + tt + 1) * JT + j4 + k * 16;
                float4 av = make_float4(0.f,0.f,0.f,0.f), sv = make_float4(0.f,0.f,0.f,0.f);
                if (irow < N) {
                    if (j + 3 < N) {
                        av = *(const float4*)&adjb[(size_t)il * N + j];
                        sv = *(const float4*)&sbb[j];
                    } else {
                        float* ap = (float*)&av; float* sp = (float*)&sv;
                        for (int r = 0; r < 4; ++r)
                            if (j + r < N) { ap[r] = adjb[(size_t)il * N + j + r]; sp[r] = sbb[j + r]; }
                    }
                }
                a4[k] = av; s4[k] = sv;
            }
        }
        bf16x8 afrag = *(const bf16x8*)&sm.wsA[cur][wv][lane][0];
#pragma unroll
        for (int nt = 0; nt < 8; ++nt) {
            bf16x8 bfrag = *(const bf16x8*)&sm.hsT[cur][nt * 16 + nlow][nquad * 8];
            acc[nt] = __builtin_amdgcn_mfma_f32_16x16x32_bf16(afrag, bfrag, acc[nt], 0, 0, 0);
        }
    }
    // z: reduce over the 4 threads sharing row il
    zacc += __shfl_xor(zacc, 1, 64);
    zacc += __shfl_xor(zacc, 2, 64);
    size_t rowsTot = (size_t)8 * N;
    float* pp = P.pp + ((size_t)split * rowsTot + (size_t)b * N) * HD;
#pragma unroll
    for (int nt = 0; nt < 8; ++nt)
#pragma unroll
        for (int r = 0; r < 4; ++r) {
            int row = i0 + wv * 16 + nquad * 4 + r;
            if (row < N) pp[(size_t)row * HD + nt * 16 + nlow] = acc[nt][r];
        }
    if ((t & 3) == 0 && irow < N)
        P.zp[(size_t)split * rowsTot + (size_t)b * N + irow] = zacc;
}

__global__ __launch_bounds__(256)
void agg2_k(AggP V, AggP O, int GVb) {
    __shared__ SharedAggM sm;
    int bid = blockIdx.x;
    if (bid < GVb) agg_body(sm, V, bid);
    else           agg_body(sm, O, bid - GVb);
}

// ---------------- 256-thread fp32 tile FMA (cross kernels) ----------------
__device__ __forceinline__ void tile_fma256(const float (*hs)[HD], const float (*ws)[WP],
                                            int rg, int c0, float acc[4][8]) {
#pragma unroll 8
    for (int jl = 0; jl < JT; ++jl) {
        float4 h0 = *(const float4*)&hs[jl][c0];
        float4 h1 = *(const float4*)&hs[jl][c0 + 64];
        float4 w4 = *(const float4*)&ws[jl][rg * 4];
        float wq[4] = {w4.x, w4.y, w4.z, w4.w};
#pragma unroll
        for (int q = 0; q < 4; ++q) {
            float w = wq[q];
            acc[q][0] = fmaf(w, h0.x, acc[q][0]);
            acc[q][1] = fmaf(w, h0.y, acc[q][1]);
            acc[q][2] = fmaf(w, h0.z, acc[q][2]);
            acc[q][3] = fmaf(w, h0.w, acc[q][3]);
            acc[q][4] = fmaf(w, h1.x, acc[q][4]);
            acc[q][5] = fmaf(w, h1.y, acc[q][5]);
            acc[q][6] = fmaf(w, h1.z, acc[q][6]);
            acc[q][7] = fmaf(w, h1.w, acc[q][7]);
        }
    }
}

__device__ __forceinline__ void part_store256(float* __restrict__ pp, size_t base,
                                              int i0, int N, int rg, int c0,
                                              float acc[4][8]) {
#pragma unroll
    for (int q = 0; q < 4; ++q) {
        int i = i0 + rg * 4 + q;
        if (i >= N) continue;
        float* op = pp + base + (size_t)i * HD;
        *(float4*)&op[c0]      = make_float4(acc[q][0], acc[q][1], acc[q][2], acc[q][3]);
        *(float4*)&op[c0 + 64] = make_float4(acc[q][4], acc[q][5], acc[q][6], acc[q][7]);
    }
}

struct SharedTile { float hs[2][JT][HD]; float ws[2][JT][WP]; };

// ---------------- fused cross (vo + ov), pipelined fp32 ----------------
__device__ void cross_vo_body(SharedTile& sm, const CrossP& P, int lbid) {
    int tiles = P.tiles;
    int split = lbid / (8 * tiles);
    int rem = lbid - split * 8 * tiles;
    int b = rem / tiles;
    int i0 = (rem - b * tiles) * IT;
    int NVl = P.iN, NOl = P.jN;
    int j_begin = split * P.tps * JT;
    if (j_begin >= NOl) return;
    int j_end = j_begin + P.tps * JT;
    if (j_end > NOl) j_end = NOl;
    int T = (j_end - j_begin + JT - 1) / JT;
    int t = threadIdx.x;
    int rg = t >> 4, c0 = (t & 15) * 4;
    int il = t & 63, jlb = t >> 6;
    float acc[4][8];
#pragma unroll
    for (int q = 0; q < 4; ++q)
#pragma unroll
        for (int x = 0; x < 8; ++x) acc[q][x] = 0.f;
    const float* Ab = P.A + (size_t)b * NOl * NVl;
    const float* srcb = P.src + (size_t)b * NOl * HD;
    int v = i0 + il;
    float w8[8];
    stage_tile_async(srcb + (size_t)j_begin * HD, &sm.hs[0][0][0], t);
#pragma unroll
    for (int k = 0; k < 8; ++k) {
        int o = j_begin + jlb + k * 4;
        w8[k] = (v < NVl && o < NOl) ? Ab[(size_t)o * NVl + v] : 0.f;
    }
    for (int tt = 0; tt < T; ++tt) {
        int cur = tt & 1;
#pragma unroll
        for (int k = 0; k < 8; ++k) sm.ws[cur][jlb + k * 4][il] = w8[k];
        __syncthreads();
        if (tt + 1 < T) {
            int jn = j_begin + (tt + 1) * JT;
            stage_tile_async(srcb + (size_t)jn * HD, &sm.hs[1 - cur][0][0], t);
#pragma unroll
            for (int k = 0; k < 8; ++k) {
                int o = jn + jlb + k * 4;
                w8[k] = (v < NVl && o < NOl) ? Ab[(size_t)o * NVl + v] : 0.f;
            }
        }
        tile_fma256(sm.hs[cur], sm.ws[cur], rg, c0, acc);
    }
    size_t rowsTot = (size_t)8 * NVl;
    part_store256(P.pp, ((size_t)split * rowsTot + (size_t)b * NVl) * HD, i0, NVl, rg, c0, acc);
}

__device__ void cross_ov_body(SharedTile& sm, const CrossP& P, int lbid) {
    int tiles = P.tiles;
    int split = lbid / (8 * tiles);
    int rem = lbid - split * 8 * tiles;
    int b = rem / tiles;
    int i0 = (rem - b * tiles) * IT;
    int NOl = P.iN, NVl = P.jN;
    int j_begin = split * P.tps * JT;
    if (j_begin >= NVl) return;
    int j_end = j_begin + P.tps * JT;
    if (j_end > NVl) j_end = NVl;
    int T = (j_end - j_begin + JT - 1) / JT;
    int t = threadIdx.x;
    int rg = t >> 4, c0 = (t & 15) * 4;
    int il = t >> 2, j4 = (t & 3) * 4;
    float acc[4][8];
#pragma unroll
    for (int q = 0; q < 4; ++q)
#pragma unroll
        for (int x = 0; x < 8; ++x) acc[q][x] = 0.f;
    const float* Ab = P.A + (size_t)b * NOl * NVl;
    const float* srcb = P.src + (size_t)b * NVl * HD;
    const float* r1b = P.rs1 + (size_t)b * NVl;
    int orow = i0 + il;
    float4 a4[2], r4[2];
    stage_tile_async(srcb + (size_t)j_begin * HD, &sm.hs[0][0][0], t);
#pragma unroll
    for (int k = 0; k < 2; ++k) {
        int vv = j_begin + j4 + k * 16;
        float4 av = make_float4(0.f,0.f,0.f,0.f), rv = make_float4(0.f,0.f,0.f,0.f);
        if (orow < NOl) {
            if (vv + 3 < NVl) {
                av = *(const float4*)&Ab[(size_t)orow * NVl + vv];
                rv = *(const float4*)&r1b[vv];
            } else {
                float* ap = (float*)&av; float* rp = (float*)&rv;
                for (int r = 0; r < 4; ++r)
                    if (vv + r < NVl) { ap[r] = Ab[(size_t)orow * NVl + vv + r]; rp[r] = r1b[vv + r]; }
            }
        }
        a4[k] = av; r4[k] = rv;
    }
    for (int tt = 0; tt < T; ++tt) {
        int cur = tt & 1;
#pragma unroll
        for (int k = 0; k < 2; ++k) {
            float wv[4] = {a4[k].x * r4[k].x, a4[k].y * r4[k].y,
                           a4[k].z * r4[k].z, a4[k].w * r4[k].w};
#pragma unroll
            for (int r = 0; r < 4; ++r) sm.ws[cur][j4 + r + k * 16][il] = wv[r];
        }
        __syncthreads();
        if (tt + 1 < T) {
            int jn = j_begin + (tt + 1) * JT;
            stage_tile_async(srcb + (size_t)jn * HD, &sm.hs[1 - cur][0][0], t);
#pragma unroll
            for (int k = 0; k < 2; ++k) {
                int vv = jn + j4 + k * 16;
                float4 av = make_float4(0.f,0.f,0.f,0.f), rv = make_float4(0.f,0.f,0.f,0.f);
                if (orow < NOl) {
                    if (vv + 3 < NVl) {
                        av = *(const float4*)&Ab[(size_t)orow * NVl + vv];
                        rv = *(const float4*)&r1b[vv];
                    } else {
                        float* ap = (float*)&av; float* rp = (float*)&rv;
                        for (int r = 0; r < 4; ++r)
                            if (vv + r < NVl) { ap[r] = Ab[(size_t)orow * NVl + vv + r]; rp[r] = r1b[vv + r]; }
                    }
                }
                a4[k] = av; r4[k] = rv;
            }
        }
        tile_fma256(sm.hs[cur], sm.ws[cur], rg, c0, acc);
    }
    size_t rowsTot = (size_t)8 * NOl;
    part_store256(P.pp, ((size_t)split * rowsTot + (size_t)b * NOl) * HD, i0, NOl, rg, c0, acc);
}

__global__ __launch_bounds__(256)
void cross2_k(CrossP VO, CrossP OV, int GVOb) {
    __shared__ SharedTile sm;
    int bid = blockIdx.x;
    if (bid < GVOb) cross_vo_body(sm, VO, bid);
    else            cross_ov_body(sm, OV, bid - GVOb);
}

// ---------------- fused finalize GAT: sum S partials, /Z, relu ----------------
__global__ __launch_bounds__(256)
void fin2_k(FinP V, FinP O, int GVb) {
    int bid = blockIdx.x;
    const FinP& P = (bid < GVb) ? V : O;
    int idx = ((bid < GVb) ? bid : bid - GVb) * 256 + threadIdx.x;
    int rows = P.rows;
    int row = idx >> 5;
    if (row >= rows) return;
    float4 v = make_float4(0.f, 0.f, 0.f, 0.f);
    for (int s = 0; s < P.S; ++s) {
        float4 p = ((const float4*)P.pp)[((size_t)s * rows + row) * 32 + (idx & 31)];
        v.x += p.x; v.y += p.y; v.z += p.z; v.w += p.w;
    }
    float z = 0.f;
    for (int s = 0; s < P.S; ++s) z += P.zp[(size_t)s * rows + row];
    float sc = 1.f / z;
    v.x = fmaxf(v.x * sc, 0.f); v.y = fmaxf(v.y * sc, 0.f);
    v.z = fmaxf(v.z * sc, 0.f); v.w = fmaxf(v.w * sc, 0.f);
    ((float4*)P.out)[idx] = v;
}

// ---------------- fused MLP: out = (relu(x@W1+b1))@W2 + b2 + res ----------------
__global__ __launch_bounds__(128)
void mlp2_k(MlpP V, MlpP O, int GVb) {
    __shared__ float xs[8][HD];
    __shared__ float hh[8][HD];
    int bid = blockIdx.x;
    const MlpP& P = (bid < GVb) ? V : O;
    int row0 = ((bid < GVb) ? bid : bid - GVb) * 8;
    int rows = P.rows;
    int t = threadIdx.x;
    for (int l = t; l < 8 * 32; l += 128) {
        int r = l >> 5, c4 = l & 31;
        int row = row0 + r;
        float4 v = make_float4(0.f, 0.f, 0.f, 0.f);
        if (row < rows) {
            for (int s = 0; s < P.S; ++s) {
                float4 p = ((const float4*)P.pp)[((size_t)s * rows + row) * 32 + c4];
                v.x += p.x; v.y += p.y; v.z += p.z; v.w += p.w;
            }
            float sc = P.scale[row];
            v.x *= sc; v.y *= sc; v.z *= sc; v.w *= sc;
        }
        ((float4*)&xs[r][0])[c4] = v;
    }
    __syncthreads();
    int wv = t >> 6, tt = t & 63, rb = wv * 4;
    float a0[4] = {0.f, 0.f, 0.f, 0.f}, a1v[4] = {0.f, 0.f, 0.f, 0.f};
#pragma unroll 4
    for (int k = 0; k < HD; ++k) {
        float w0 = P.W1[(size_t)k * HD + tt];
        float w1 = P.W1[(size_t)k * HD + tt + 64];
#pragma unroll
        for (int r = 0; r < 4; ++r) {
            float x = xs[rb + r][k];
            a0[r] = fmaf(x, w0, a0[r]);
            a1v[r] = fmaf(x, w1, a1v[r]);
        }
    }
    float bb0 = P.b1[tt], bb1 = P.b1[tt + 64];
#pragma unroll
    for (int r = 0; r < 4; ++r) {
        hh[rb + r][tt]      = fmaxf(a0[r] + bb0, 0.f);
        hh[rb + r][tt + 64] = fmaxf(a1v[r] + bb1, 0.f);
    }
    __syncthreads();
    float c0a[4] = {0.f, 0.f, 0.f, 0.f}, c1a[4] = {0.f, 0.f, 0.f, 0.f};
#pragma unroll 4
    for (int k = 0; k < HD; ++k) {
        float w0 = P.W2[(size_t)k * HD + tt];
        float w1 = P.W2[(size_t)k * HD + tt + 64];
#pragma unroll
        for (int r = 0; r < 4; ++r) {
            float x = hh[rb + r][k];
            c0a[r] = fmaf(x, w0, c0a[r]);
            c1a[r] = fmaf(x, w1, c1a[r]);
        }
    }
    float d0 = P.b2[tt], d1 = P.b2[tt + 64];
#pragma unroll
    for (int r = 0; r < 4; ++r) {
        int row = row0 + rb + r;
        if (row >= rows) continue;
        P.out[(size_t)row * HD + tt]      = c0a[r] + d0 + P.res[(size_t)row * HD + tt];
        P.out[(size_t)row * HD + tt + 64] = c1a[r] + d1 + P.res[(size_t)row * HD + tt + 64];
    }
}

// ---------------- output projection ----------------
template<int RELU, int BIAS, int RES>
__global__ __launch_bounds__(128)
void linear_k(const float* __restrict__ X, const float* __restrict__ W,
              const float* __restrict__ bias, const float* __restrict__ res,
              float* __restrict__ out, int rows, int K, int Dout) {
    __shared__ float xs[4][512];
    int row0 = blockIdx.x * 4;
    int t = threadIdx.x;
    int K4 = K >> 2;
    for (int l = t; l < 4 * K4; l += 128) {
        int r = l / K4, c4 = l - r * K4;
        float4 val = make_float4(0.f, 0.f, 0.f, 0.f);
        if (row0 + r < rows) val = ((const float4*)(X + (size_t)(row0 + r) * K))[c4];
        ((float4*)&xs[r][0])[c4] = val;
    }
    __syncthreads();
    int chunk = Dout < 256 ? Dout : 256;
    int half = chunk >> 1;
    if (t >= half) return;
    int c0 = blockIdx.y * chunk + t;
    int c1 = c0 + half;
    float a00 = 0, a01 = 0, a02 = 0, a03 = 0, a10 = 0, a11 = 0, a12 = 0, a13 = 0;
#pragma unroll 4
    for (int k = 0; k < K; ++k) {
        float w0 = W[(size_t)k * Dout + c0];
        float w1 = W[(size_t)k * Dout + c1];
        float x0 = xs[0][k], x1 = xs[1][k], x2 = xs[2][k], x3 = xs[3][k];
        a00 = fmaf(x0, w0, a00); a01 = fmaf(x1, w0, a01);
        a02 = fmaf(x2, w0, a02); a03 = fmaf(x3, w0, a03);
        a10 = fmaf(x0, w1, a10); a11 = fmaf(x1, w1, a11);
        a12 = fmaf(x2, w1, a12); a13 = fmaf(x3, w1, a13);
    }
    float accs[2][4] = {{a00, a01, a02, a03}, {a10, a11, a12, a13}};
    int cs[2] = {c0, c1};
    for (int h = 0; h < 2; ++h) {
        float bv = BIAS ? bias[cs[h]] : 0.f;
        for (int r = 0; r < 4; ++r) {
            int row = row0 + r;
            if (row >= rows) continue;
            float v = accs[h][r] + bv;
            if (RES) v += res[(size_t)row * Dout + cs[h]];
            if (RELU) v = fmaxf(v, 0.f);
            out[(size_t)row * Dout + cs[h]] = v;
        }
    }
}

// ---------------- host launcher ----------------
extern "C" void kernel_launch(void* const* d_in, const int* in_sizes, int n_in,
                              void* d_out, int out_size, void* d_ws, size_t ws_size,
                              hipStream_t stream) {
    const int B = 8, NV = 500, NO = 1500, DV = 512, DO = 32;
    const float* vis_memory = (const float*)d_in[0];
    const float* obj_memory = (const float*)d_in[1];
    const float* vis_adj    = (const float*)d_in[2];
    const float* obj_adj    = (const float*)d_in[3];
    const float* A_OV       = (const float*)d_in[4];
    const float* Wv1  = (const float*)d_in[5];
    const float* av1a = (const float*)d_in[6];
    const float* av1b = (const float*)d_in[7];
    const float* Wv2  = (const float*)d_in[8];
    const float* av2a = (const float*)d_in[9];
    const float* av2b = (const float*)d_in[10];
    const float* Wo1  = (const float*)d_in[11];
    const float* ao1a = (const float*)d_in[12];
    const float* ao1b = (const float*)d_in[13];
    const float* Wo2  = (const float*)d_in[14];
    const float* ao2a = (const float*)d_in[15];
    const float* ao2b = (const float*)d_in[16];
    const float* g2o_W1 = (const float*)d_in[17];
    const float* g2o_b1 = (const float*)d_in[18];
    const float* g2o_W2 = (const float*)d_in[19];
    const float* g2o_b2 = (const float*)d_in[20];
    const float* o2g_W1 = (const float*)d_in[21];
    const float* o2g_b1 = (const float*)d_in[22];
    const float* o2g_W2 = (const float*)d_in[23];
    const float* o2g_b2 = (const float*)d_in[24];
    const float* img_W = (const float*)d_in[25];
    const float* img_b = (const float*)d_in[26];
    const float* obj_W = (const float*)d_in[27];
    const float* obj_b = (const float*)d_in[28];

    const int tilesJV = 16, tilesJO = 47;            // ceil(N/32)

    float* wsp = (float*)d_ws;
    size_t off = 0;
    auto alloc = [&](size_t n) { float* p = wsp + off; off += (n + 3) & ~(size_t)3; return p; };
    float* rs1   = alloc(B * NV);
    float* rs2   = alloc(B * NO);
    float* saV   = alloc(B * NV);
    float* sbV   = alloc(B * NV);
    float* smV   = alloc(B);
    float* saO   = alloc(B * NO);
    float* sbO   = alloc(B * NO);
    float* smO   = alloc(B);
    float* s1p   = alloc((size_t)B * CCH * NV);
    // weight-prep outputs (bf16 transposed W + score vectors)
    unsigned short* WTv1 = (unsigned short*)alloc(128 * 512 / 2);
    unsigned short* WTo1 = (unsigned short*)alloc(128 * 32 / 2);
    unsigned short* WTv2 = (unsigned short*)alloc(128 * 128 / 2);
    unsigned short* WTo2 = (unsigned short*)alloc(128 * 128 / 2);
    float* wav1a = alloc(512); float* wav1b = alloc(512);
    float* wao1a = alloc(32);  float* wao1b = alloc(32);
    float* wav2a = alloc(128); float* wav2b = alloc(128);
    float* wao2a = alloc(128); float* wao2b = alloc(128);
    // bf16 X buffers (max over layers: vis 4000x512, obj 12000x128)
    unsigned short* XbfV = (unsigned short*)alloc((size_t)B * NV * 512 / 2);
    unsigned short* XbfO = (unsigned short*)alloc((size_t)B * NO * 128 / 2);
    unsigned short* hTv = (unsigned short*)alloc((size_t)B * tilesJV * 4096 / 2);
    unsigned short* hTo = (unsigned short*)alloc((size_t)B * tilesJO * 4096 / 2);
    float* v1    = alloc((size_t)B * NV * HD);
    float* o1    = alloc((size_t)B * NO * HD);
    float* visb  = alloc((size_t)B * NV * HD);
    float* objb  = alloc((size_t)B * NO * HD);
    float* ppV   = alloc((size_t)8 * B * NV * HD);
    float* zpV   = alloc((size_t)8 * B * NV);
    float* ppO   = alloc((size_t)4 * B * NO * HD);
    float* zpO   = alloc((size_t)4 * B * NO);
    alloc(16384);                                    // tail pad for async/OOB reads

    // weight prep (once): 16 + 1 + 4 + 4 = 25 blocks
    {
        WprepP w0{Wv1, av1a, av1b, WTv1, wav1a, wav1b, DV};
        WprepP w1{Wo1, ao1a, ao1b, WTo1, wao1a, wao1b, DO};
        WprepP w2{Wv2, av2a, av2b, WTv2, wav2a, wav2b, HD};
        WprepP w3{Wo2, ao2a, ao2b, WTo2, wao2a, wao2b, HD};
        wprep_k<<<25, 256, 0, stream>>>(w0, w1, w2, w3, 16, 17, 21);
    }

    colsum_part_k<<<dim3((NV + 255) / 256, CCH, B), 256, 0, stream>>>(A_OV, s1p, B, NO, NV);
    colsum_fin_k<<<dim3((B * NV + 255) / 256), 256, 0, stream>>>(s1p, rs1, B, NV);
    rowsum_inv_k<<<dim3((B * NO + 3) / 4), 256, 0, stream>>>(A_OV, rs1, rs2, B, NO, NV);

    // geometry (IT=64, JT=32):
    const int tilesV = 8, tilesO = 24;               // ceil(N/64)
    const int SV = 8, SO = 4, SVO = 8, SOV = 4;
    const int tpsV = 2;    // ceil(16/8)  j-tiles per split (vis GAT)
    const int tpsO = 12;   // ceil(47/4)  j-tiles per split (obj GAT)
    const int tpsVO = 6;   // ceil(ceil(1500/32)/8)
    const int tpsOV = 4;   // ceil(ceil(500/32)/4)
    const int G_AGG_V = B * tilesV * SV;             // 512
    const int G_AGG_O = B * tilesO * SO;             // 768
    const int G_CR_VO = B * tilesV * SVO;            // 512
    const int G_CR_OV = B * tilesO * SOV;            // 768
    const int G_MLP_V = B * NV / 8;                  // 500
    const int G_MLP_O = B * NO / 8;                  // 1500
    const int G_FIN_V = B * NV * 32 / 256;           // 500
    const int G_FIN_O = B * NO * 32 / 256;           // 1500
    const int G_XP_V = B * NV / 4;                   // 1000
    const int G_XP_O = B * NO / 4;                   // 3000
    const int G_GMF_V = B * tilesJV;                 // 128
    const int G_GMF_O = B * tilesJO;                 // 376

    // shared per-layer tail (everything after h/scores are computed)
    auto tail = [&](float* visout, float* objout) {
        sbmax2_k<<<16, 256, 0, stream>>>(sbV, smV, sbO, smO, NV, NO);
        AggP av{vis_adj, saV, sbV, smV, hTv, ppV, zpV, NV, tilesV, tilesJV, tpsV};
        AggP ao{obj_adj, saO, sbO, smO, hTo, ppO, zpO, NO, tilesO, tilesJO, tpsO};
        agg2_k<<<G_AGG_V + G_AGG_O, THR, 0, stream>>>(av, ao, G_AGG_V);
        FinP fv{ppV, zpV, v1, B * NV, SV};
        FinP fo{ppO, zpO, o1, B * NO, SO};
        fin2_k<<<G_FIN_V + G_FIN_O, 256, 0, stream>>>(fv, fo, G_FIN_V);
        CrossP cvo{A_OV, o1, nullptr, ppV, NV, NO, tilesV, tpsVO};
        CrossP cov{A_OV, v1, rs1, ppO, NO, NV, tilesO, tpsOV};
        cross2_k<<<G_CR_VO + G_CR_OV, THR, 0, stream>>>(cvo, cov, G_CR_VO);
        MlpP mv{ppV, rs1, SVO, o2g_W1, o2g_b1, o2g_W2, o2g_b2, v1, visout, B * NV};
        MlpP mo{ppO, rs2, SOV, g2o_W1, g2o_b1, g2o_W2, g2o_b2, o1, objout, B * NO};
        mlp2_k<<<G_MLP_V + G_MLP_O, 128, 0, stream>>>(mv, mo, G_MLP_V);
    };

    // ---- layer 1 (Kv=512, Ko=32) ----
    {
        XprepP xv{vis_memory, XbfV, wav1a, wav1b, saV, sbV, B * NV};
        XprepP xo{obj_memory, XbfO, wao1a, wao1b, saO, sbO, B * NO};
        xprep2_k<512, 32><<<G_XP_V + G_XP_O, 256, 0, stream>>>(xv, xo, G_XP_V);
        GmfP gv{XbfV, WTv1, hTv, NV, tilesJV};
        GmfP go{XbfO, WTo1, hTo, NO, tilesJO};
        gmf2_k<512, 32><<<G_GMF_V + G_GMF_O, 256, 0, stream>>>(gv, go, G_GMF_V);
        tail(visb, objb);
    }
    // ---- layer 2 (Kv=Ko=128) ----
    {
        XprepP xv{visb, XbfV, wav2a, wav2b, saV, sbV, B * NV};
        XprepP xo{objb, XbfO, wao2a, wao2b, saO, sbO, B * NO};
        xprep2_k<128, 128><<<G_XP_V + G_XP_O, 256, 0, stream>>>(xv, xo, G_XP_V);
        GmfP gv{XbfV, WTv2, hTv, NV, tilesJV};
        GmfP go{XbfO, WTo2, hTo, NO, tilesJO};
        gmf2_k<128, 128><<<G_GMF_V + G_GMF_O, 256, 0, stream>>>(gv, go, G_GMF_V);
        tail(visb, objb);
    }

    // output projections
    float* vis_out = (float*)d_out;
    float* obj_out = vis_out + (size_t)B * NV * DV;
    linear_k<0, 1, 0><<<dim3((B * NV + 3) / 4, (DV + 255) / 256), 128, 0, stream>>>(
        visb, img_W, img_b, nullptr, vis_out, B * NV, HD, DV);
    linear_k<0, 1, 0><<<dim3((B * NO + 3) / 4, 1), 128, 0, stream>>>(
        objb, obj_W, obj_b, nullptr, obj_out, B * NO, HD, DO);
}

// Round 2
// 601.238 us; speedup vs baseline: 1.1301x; 1.0229x over previous
//
#include <hip/hip_runtime.h>
#include <math.h>

#define EPSV 1e-5f
#define HD 128
#define IT 64
#define JT 32
#define WP 68
#define CCH 16
#define THR 256

typedef __attribute__((address_space(3))) uint32_t lds_u32_t;
typedef __attribute__((address_space(1))) uint32_t gbl_u32_t;
typedef __attribute__((ext_vector_type(8))) short bf16x8;
typedef __attribute__((ext_vector_type(4))) float f32x4;

__device__ __forceinline__ void async_copy16(const float* g, float* l) {
    __builtin_amdgcn_global_load_lds((const gbl_u32_t*)g, (lds_u32_t*)l, 16, 0, 0);
}

// stage a JT x HD fp32 tile (16 KB) global -> LDS via async DMA (256 threads)
__device__ __forceinline__ void stage_tile_async(const float* gsrc, float* lds, int t) {
    int wv = t >> 6, lane = t & 63;
#pragma unroll
    for (int it = 0; it < 4; ++it) {
        int c = it * 4 + wv;
        async_copy16(gsrc + c * 256 + lane * 4, lds + c * 256);
    }
}

// stage an 8 KB bf16 tile global -> LDS via async DMA (256 threads, 2 insts)
__device__ __forceinline__ void stage_8k(const void* g, void* l, int t) {
    const float* gf = (const float*)g; float* lf = (float*)l;
    async_copy16(gf + t * 4, lf + t * 4);
    async_copy16(gf + t * 4 + 1024, lf + t * 4 + 1024);
}

__device__ __forceinline__ unsigned int f2bf(float f) {
    return __builtin_bit_cast(unsigned int, f) >> 16;
}

// round-to-nearest-even fp32 -> bf16
__device__ __forceinline__ unsigned short rne_bf16(float f) {
    unsigned int u = __builtin_bit_cast(unsigned int, f);
    u += 0x7FFFu + ((u >> 16) & 1u);
    return (unsigned short)(u >> 16);
}

// ---------------- param structs ----------------
struct WprepP { const float *W, *a1, *a2; unsigned short* WT; float *wa1, *wa2; int K; };
struct XprepP { const float* X; unsigned short* Xbf; const float *wa1, *wa2;
                float *sa, *sb; int rows; };
struct GmfP   { const unsigned short *Xbf, *WT; unsigned short* hT; int N, tilesJ; };
struct AggP  { const float *adj, *sa, *sb, *sm; const unsigned short* hT;
               float *pp, *zp; int N, tiles, tilesJ, tps; };
struct CrossP{ const float *A, *src, *rs1; float *pp; int iN, jN, tiles, tps; };
struct FinP  { const float *pp, *zp; float *out; int rows, S; };
struct MlpP  { const float *pp, *scale; int S; const float *W1, *b1, *W2, *b2, *res;
               float *out; int rows; };

// ---------------- normalization scale kernels ----------------

__global__ void colsum_part_k(const float* __restrict__ A, float* __restrict__ s1p,
                              int B, int NO, int NV) {
    int v = blockIdx.x * 256 + threadIdx.x;
    int c = blockIdx.y, b = blockIdx.z;
    if (v >= NV) return;
    int chunk = (NO + CCH - 1) / CCH;
    int o0 = c * chunk;
    int o1 = o0 + chunk; if (o1 > NO) o1 = NO;
    const float* Ab = A + (size_t)b * NO * NV + v;
    float s = 0.f;
    for (int o = o0; o < o1; ++o) s += Ab[(size_t)o * NV];
    s1p[((size_t)b * CCH + c) * NV + v] = s;
}

__global__ void colsum_fin_k(const float* __restrict__ s1p, float* __restrict__ rs1,
                             int B, int NV) {
    int idx = blockIdx.x * 256 + threadIdx.x;
    if (idx >= B * NV) return;
    int b = idx / NV, v = idx - b * NV;
    float s = 0.f;
    for (int c = 0; c < CCH; ++c) s += s1p[((size_t)b * CCH + c) * NV + v];
    rs1[idx] = 1.f / (s + EPSV);
}

__global__ void rowsum_inv_k(const float* __restrict__ A, const float* __restrict__ rs1,
                             float* __restrict__ rs2, int B, int NO, int NV) {
    int row = blockIdx.x * (blockDim.x >> 6) + (threadIdx.x >> 6);
    int lane = threadIdx.x & 63;
    if (row >= B * NO) return;
    int b = row / NO;
    const float* Ar = A + (size_t)row * NV;
    const float* r1 = rs1 + (size_t)b * NV;
    float s = 0.f;
    for (int v = lane; v < NV; v += 64) s += Ar[v] * r1[v];
    for (int off = 32; off; off >>= 1) s += __shfl_xor(s, off, 64);
    if (lane == 0) rs2[row] = 1.f / (s + EPSV);
}

// ---------------- weight prep (runs once): WT[c][k] bf16 + wa1/wa2 = W @ a ----------
__global__ __launch_bounds__(256)
void wprep_k(WprepP p0, WprepP p1, WprepP p2, WprepP p3, int e0, int e1, int e2) {
    __shared__ float lw[32][129];
    __shared__ float a1s[128], a2s[128];
    int bid = blockIdx.x;
    const WprepP& P = bid < e0 ? p0 : bid < e1 ? p1 : bid < e2 ? p2 : p3;
    int lb = bid < e0 ? bid : bid < e1 ? bid - e0 : bid < e2 ? bid - e1 : bid - e2;
    int k0 = lb * 32, K = P.K;
    int t = threadIdx.x;
    if (t < 128) { a1s[t] = P.a1[t]; a2s[t] = P.a2[t]; }
    for (int idx = t; idx < 32 * 32; idx += 256) {   // float4 granularity
        int kk = idx >> 5, c4 = idx & 31;
        float4 v = ((const float4*)(P.W + (size_t)(k0 + kk) * 128))[c4];
        lw[kk][c4 * 4 + 0] = v.x; lw[kk][c4 * 4 + 1] = v.y;
        lw[kk][c4 * 4 + 2] = v.z; lw[kk][c4 * 4 + 3] = v.w;
    }
    __syncthreads();
    // wa1/wa2: 8 lanes per k-row
    int kk = t >> 3, g = t & 7;
    float s1 = 0.f, s2 = 0.f;
    for (int c = g; c < 128; c += 8) {
        float w = lw[kk][c];
        s1 = fmaf(w, a1s[c], s1);
        s2 = fmaf(w, a2s[c], s2);
    }
    s1 += __shfl_xor(s1, 1, 64); s1 += __shfl_xor(s1, 2, 64); s1 += __shfl_xor(s1, 4, 64);
    s2 += __shfl_xor(s2, 1, 64); s2 += __shfl_xor(s2, 2, 64); s2 += __shfl_xor(s2, 4, 64);
    if (g == 0) { P.wa1[k0 + kk] = s1; P.wa2[k0 + kk] = s2; }
    // transposed bf16 store: WT[c][k]
    for (int idx = t; idx < 4096; idx += 256) {
        int c = idx >> 5, k = idx & 31;
        P.WT[(size_t)c * K + k0 + k] = rne_bf16(lw[k][c]);
    }
}

// ---------------- X prep: Xbf = rne_bf16(X); sa = X.wa1, sb = X.wa2 (exact fp32) ----
template<int K>
__device__ void xprep_body(const XprepP& P, int lb) {
    int t = threadIdx.x, wv = t >> 6, lane = t & 63;
    int row = lb * 4 + wv;
    if (row >= P.rows) return;
    const float4* x4 = (const float4*)(P.X + (size_t)row * K);
    const float4* w14 = (const float4*)P.wa1;
    const float4* w24 = (const float4*)P.wa2;
    unsigned short* xb = P.Xbf + (size_t)row * K;
    float s1 = 0.f, s2 = 0.f;
    constexpr int K4 = K / 4;
    constexpr int NI = (K4 + 63) / 64;
#pragma unroll
    for (int i = 0; i < NI; ++i) {
        int k4 = i * 64 + lane;
        if ((K4 % 64 == 0) || (k4 < K4)) {
            float4 x = x4[k4];
            float4 a = w14[k4];
            float4 b = w24[k4];
            s1 += x.x * a.x + x.y * a.y + x.z * a.z + x.w * a.w;
            s2 += x.x * b.x + x.y * b.y + x.z * b.z + x.w * b.w;
            ushort4 p = make_ushort4(rne_bf16(x.x), rne_bf16(x.y),
                                     rne_bf16(x.z), rne_bf16(x.w));
            *(ushort4*)(xb + (size_t)k4 * 4) = p;
        }
    }
#pragma unroll
    for (int off = 32; off; off >>= 1) {
        s1 += __shfl_xor(s1, off, 64);
        s2 += __shfl_xor(s2, off, 64);
    }
    if (lane == 0) { P.sa[row] = s1; P.sb[row] = s2; }
}

template<int KV, int KO>
__global__ __launch_bounds__(256)
void xprep2_k(XprepP V, XprepP O, int GV) {
    int bid = blockIdx.x;
    if (bid < GV) xprep_body<KV>(V, bid);
    else          xprep_body<KO>(O, bid - GV);
}

// ---------------- MFMA h-GEMM producing hT directly ----------------
// D[m=c][n=jl] = sum_k WT[c][k] * Xbf[row0+jl][k]  via mfma_f32_16x16x32_bf16.
// A-frag: A[m=lane&15][k=quad*8+i]; B-frag: B[k=quad*8+i][n=lane&15];
// C/D: col=lane&15 (jl), row=quad*4+reg (c)  — same conventions as agg2_k (verified).
template<int K>
__device__ void gmf_body(const GmfP& P, int lb) {
    int tilesJ = P.tilesJ, N = P.N;
    int b = lb / tilesJ, jt = lb - b * tilesJ;
    int t = threadIdx.x, wv = t >> 6, lane = t & 63;
    int ml = lane & 15, quad = lane >> 4;
    const unsigned short* xb = P.Xbf + ((size_t)b * N + (size_t)jt * 32) * K;
    const unsigned short* wt0 = P.WT + (size_t)(wv * 32 + ml) * K;
    const unsigned short* wt1 = wt0 + (size_t)16 * K;
    const unsigned short* xb0 = xb + (size_t)ml * K;
    const unsigned short* xb1 = xb + (size_t)(16 + ml) * K;
    f32x4 acc00 = {0.f, 0.f, 0.f, 0.f}, acc01 = acc00, acc10 = acc00, acc11 = acc00;
#pragma unroll 4
    for (int kt = 0; kt < K / 32; ++kt) {
        int kk = kt * 32 + quad * 8;
        bf16x8 a0 = *(const bf16x8*)(wt0 + kk);
        bf16x8 a1 = *(const bf16x8*)(wt1 + kk);
        bf16x8 b0 = *(const bf16x8*)(xb0 + kk);
        bf16x8 b1 = *(const bf16x8*)(xb1 + kk);
        acc00 = __builtin_amdgcn_mfma_f32_16x16x32_bf16(a0, b0, acc00, 0, 0, 0);
        acc01 = __builtin_amdgcn_mfma_f32_16x16x32_bf16(a0, b1, acc01, 0, 0, 0);
        acc10 = __builtin_amdgcn_mfma_f32_16x16x32_bf16(a1, b0, acc10, 0, 0, 0);
        acc11 = __builtin_amdgcn_mfma_f32_16x16x32_bf16(a1, b1, acc11, 0, 0, 0);
    }
    unsigned short* hb = P.hT + (size_t)(b * tilesJ + jt) * 4096;
    int nvalid = N - jt * 32; if (nvalid > 32) nvalid = 32;
    bool ok0 = ml < nvalid, ok1 = (16 + ml) < nvalid;
    int c0 = wv * 32 + quad * 4;
#pragma unroll
    for (int r = 0; r < 4; ++r) {
        hb[(size_t)(c0 + r) * 32 + ml]           = ok0 ? rne_bf16(acc00[r]) : 0;
        hb[(size_t)(c0 + r) * 32 + 16 + ml]      = ok1 ? rne_bf16(acc01[r]) : 0;
        hb[(size_t)(c0 + 16 + r) * 32 + ml]      = ok0 ? rne_bf16(acc10[r]) : 0;
        hb[(size_t)(c0 + 16 + r) * 32 + 16 + ml] = ok1 ? rne_bf16(acc11[r]) : 0;
    }
}

template<int KV, int KO>
__global__ __launch_bounds__(256)
void gmf2_k(GmfP V, GmfP O, int GV) {
    int bid = blockIdx.x;
    if (bid < GV) gmf_body<KV>(V, bid);
    else          gmf_body<KO>(O, bid - GV);
}

// ---------------- fused per-batch sb max ----------------
__global__ __launch_bounds__(256)
void sbmax2_k(const float* __restrict__ sbV, float* __restrict__ smV,
              const float* __restrict__ sbO, float* __restrict__ smO,
              int NV, int NO) {
    __shared__ float red[256];
    int b0 = blockIdx.x, t = threadIdx.x;
    const float* sb; float* out; int N;
    if (b0 < 8) { sb = sbV + (size_t)b0 * NV; out = smV + b0; N = NV; }
    else        { sb = sbO + (size_t)(b0 - 8) * NO; out = smO + (b0 - 8); N = NO; }
    float m = -INFINITY;
    for (int j = t; j < N; j += 256) m = fmaxf(m, sb[j]);
    red[t] = m; __syncthreads();
    for (int s = 128; s; s >>= 1) {
        if (t < s) red[t] = fmaxf(red[t], red[t + s]);
        __syncthreads();
    }
    if (t == 0) *out = red[0];
}

// ---------------- MFMA GAT aggregation (vis+obj fused) ----------------
// out[IT x HD] += P[IT x JT] @ H[JT x HD] per K-tile via mfma_f32_16x16x32_bf16.
// Pipelined with counted vmcnt + raw barriers (T3/T4): adj loads prefetched
// depth-2 in registers (two named sets, no runtime indexing), hT DMA depth-1.
// Pre-barrier wait = vmcnt(4) lgkmcnt(0): drains own hT DMA (per-wave vmcnt!)
// while keeping the 4 next-next adj loads in flight across the barrier.
// adj loads are exec-uniform (clamped addresses + mask-mul) so every wave
// issues exactly the same vm-op count — required for counted waits.
struct SharedAggM {
    unsigned short hsT[2][128][32];    // [c][jl] bf16, DMA'd from hT
    unsigned short wsA[2][4][64][8];   // A-fragment order per wave
    float sa_s[IT], m_s[IT];
};

// always issues exactly 4 float4 loads (2 adj + 2 sb), addresses clamped in-bounds.
// OOB adj components are forced to 0 (=> w=0, sb garbage then irrelevant).
__device__ __forceinline__ void load_adj(const float* adjb, const float* sbb,
                                         int il, int j4, int irow, int N,
                                         int jt, float4* AR, float4* SR) {
#pragma unroll
    for (int k = 0; k < 2; ++k) {
        int j = jt * JT + j4 + k * 16;              // j % 4 == 0; N % 4 == 0
        bool okc = (j + 3) < N;
        bool ok = (irow < N) && okc;
        size_t offa = ok ? (size_t)il * N + j : 0;
        int offs = okc ? j : 0;
        float4 av = *(const float4*)(adjb + offa);
        float4 sv = *(const float4*)(sbb + offs);
        float msk = ok ? 1.f : 0.f;
        av.x *= msk; av.y *= msk; av.z *= msk; av.w *= msk;
        AR[k] = av; SR[k] = sv;
    }
}

#define AGG_TILE(tt_, CUR_, AR_, SR_) do {                                          \
    float sai_ = sm.sa_s[il], mm_ = sm.m_s[il];                                     \
    _Pragma("unroll")                                                               \
    for (int k = 0; k < 2; ++k) {                                                   \
        float av_[4] = {AR_[k].x, AR_[k].y, AR_[k].z, AR_[k].w};                    \
        float sv_[4] = {SR_[k].x, SR_[k].y, SR_[k].z, SR_[k].w};                    \
        float w_[4];                                                                \
        _Pragma("unroll")                                                           \
        for (int r = 0; r < 4; ++r) {                                               \
            float e_ = sai_ + sv_[r];                                               \
            e_ = e_ > 0.f ? e_ : 0.2f * e_;                                         \
            w_[r] = av_[r] > 0.f ? __expf(e_ - mm_) : 0.f;                          \
            zacc += w_[r];                                                          \
        }                                                                           \
        unsigned int lo_ = f2bf(w_[0]) | (__builtin_bit_cast(unsigned int, w_[1]) & 0xFFFF0000u); \
        unsigned int hi_ = f2bf(w_[2]) | (__builtin_bit_cast(unsigned int, w_[3]) & 0xFFFF0000u); \
        *(uint2*)&sm.wsA[CUR_][wv][wrow + 16 * (q0 + 2 * k)][i0w] = make_uint2(lo_, hi_); \
    }                                                                               \
    /* drain own hT DMA (oldest 2) + wsA writes; keep next-next adj (4) flying */   \
    if (tt_ + 1 < T) asm volatile("s_waitcnt vmcnt(4) lgkmcnt(0)" ::: "memory");    \
    else             asm volatile("s_waitcnt vmcnt(0) lgkmcnt(0)" ::: "memory");    \
    __builtin_amdgcn_s_barrier();                                                   \
    asm volatile("" ::: "memory");  /* no LDS-read hoisting above the barrier */    \
    if (tt_ + 1 < T) stage_8k(hTb + (size_t)(tt_ + 1) * 4096, &sm.hsT[1 - CUR_][0][0], t); \
    if (tt_ + 2 < T) load_adj(adjb, sbb, il, j4, irow, N, jt0 + tt_ + 2, AR_, SR_); \
    bf16x8 afrag_ = *(const bf16x8*)&sm.wsA[CUR_][wv][lane][0];                     \
    _Pragma("unroll")                                                               \
    for (int nt = 0; nt < 8; ++nt) {                                                \
        bf16x8 bfrag_ = *(const bf16x8*)&sm.hsT[CUR_][nt * 16 + nlow][nquad * 8];   \
        acc[nt] = __builtin_amdgcn_mfma_f32_16x16x32_bf16(afrag_, bfrag_, acc[nt], 0, 0, 0); \
    }                                                                               \
} while (0)

__device__ void agg_body(SharedAggM& sm, const AggP& P, int lbid) {
    int tiles = P.tiles;
    int split = lbid / (8 * tiles);
    int rem = lbid - split * 8 * tiles;
    int b = rem / tiles;
    int i0 = (rem - b * tiles) * IT;
    int N = P.N;
    int jt0 = split * P.tps;
    if (jt0 >= P.tilesJ) return;
    int jt1 = jt0 + P.tps; if (jt1 > P.tilesJ) jt1 = P.tilesJ;
    int T = jt1 - jt0;
    int t = threadIdx.x;
    if (t < IT) {
        int i = i0 + t;
        float s = (i < N) ? P.sa[(size_t)b * N + i] : 0.f;
        sm.sa_s[t] = s;
        float e = s + P.sm[b];
        sm.m_s[t] = e > 0.f ? e : 0.2f * e;
    }
    __syncthreads();
    int wv = t >> 6, lane = t & 63;
    // w-producer role: thread owns row il, j-offsets {j4..j4+3, j4+16..j4+19}
    int il = t >> 2, j4 = (t & 3) * 4;
    int q0 = j4 >> 3, i0w = j4 & 7, wrow = il & 15;
    // MFMA consumer role
    int nquad = lane >> 4, nlow = lane & 15;
    f32x4 acc[8];
#pragma unroll
    for (int nt = 0; nt < 8; ++nt)
#pragma unroll
        for (int r = 0; r < 4; ++r) acc[nt][r] = 0.f;
    float zacc = 0.f;
    const float* adjb = P.adj + ((size_t)b * N + i0) * N;
    const float* sbb = P.sb + (size_t)b * N;
    const unsigned short* hTb = P.hT + ((size_t)b * P.tilesJ + jt0) * 4096;
    int irow = i0 + il;
    // prologue: DMA tile0; adj regs tiles 0 and 1 (two named sets, depth-2)
    float4 aA[2], sA[2], aB[2], sB[2];
    stage_8k(hTb, &sm.hsT[0][0][0], t);
    load_adj(adjb, sbb, il, j4, irow, N, jt0, aA, sA);
    if (1 < T) load_adj(adjb, sbb, il, j4, irow, N, jt0 + 1, aB, sB);
    int tt = 0;
    while (true) {
        AGG_TILE(tt, 0, aA, sA);
        ++tt; if (tt >= T) break;
        AGG_TILE(tt, 1, aB, sB);
        ++tt; if (tt >= T) break;
    }
    // z: reduce over the 4 threads sharing row il
    zacc += __shfl_xor(zacc, 1, 64);
    zacc += __shfl_xor(zacc, 2, 64);
    size_t rowsTot = (size_t)8 * N;
    float* pp = P.pp + ((size_t)split * rowsTot + (size_t)b * N) * HD;
#pragma unroll
    for (int nt = 0; nt < 8; ++nt)
#pragma unroll
        for (int r = 0; r < 4; ++r) {
            int row = i0 + wv * 16 + nquad * 4 + r;
            if (row < N) pp[(size_t)row * HD + nt * 16 + nlow] = acc[nt][r];
        }
    if ((t & 3) == 0 && irow < N)
        P.zp[(size_t)split * rowsTot + (size_t)b * N + irow] = zacc;
}

__global__ __launch_bounds__(256)
void agg2_k(AggP V, AggP O, int GVb) {
    __shared__ SharedAggM sm;
    int bid = blockIdx.x;
    if (bid < GVb) agg_body(sm, V, bid);
    else           agg_body(sm, O, bid - GVb);
}

// ---------------- 256-thread fp32 tile FMA (cross kernels) ----------------
__device__ __forceinline__ void tile_fma256(const float (*hs)[HD], const float (*ws)[WP],
                                            int rg, int c0, float acc[4][8]) {
#pragma unroll 8
    for (int jl = 0; jl < JT; ++jl) {
        float4 h0 = *(const float4*)&hs[jl][c0];
        float4 h1 = *(const float4*)&hs[jl][c0 + 64];
        float4 w4 = *(const float4*)&ws[jl][rg * 4];
        float wq[4] = {w4.x, w4.y, w4.z, w4.w};
#pragma unroll
        for (int q = 0; q < 4; ++q) {
            float w = wq[q];
            acc[q][0] = fmaf(w, h0.x, acc[q][0]);
            acc[q][1] = fmaf(w, h0.y, acc[q][1]);
            acc[q][2] = fmaf(w, h0.z, acc[q][2]);
            acc[q][3] = fmaf(w, h0.w, acc[q][3]);
            acc[q][4] = fmaf(w, h1.x, acc[q][4]);
            acc[q][5] = fmaf(w, h1.y, acc[q][5]);
            acc[q][6] = fmaf(w, h1.z, acc[q][6]);
            acc[q][7] = fmaf(w, h1.w, acc[q][7]);
        }
    }
}

__device__ __forceinline__ void part_store256(float* __restrict__ pp, size_t base,
                                              int i0, int N, int rg, int c0,
                                              float acc[4][8]) {
#pragma unroll
    for (int q = 0; q < 4; ++q) {
        int i = i0 + rg * 4 + q;
        if (i >= N) continue;
        float* op = pp + base + (size_t)i * HD;
        *(float4*)&op[c0]      = make_float4(acc[q][0], acc[q][1], acc[q][2], acc[q][3]);
        *(float4*)&op[c0 + 64] = make_float4(acc[q][4], acc[q][5], acc[q][6], acc[q][7]);
    }
}

struct SharedTile { float hs[2][JT][HD]; float ws[2][JT][WP]; };

// ---------------- fused cross (vo + ov), pipelined fp32 ----------------
__device__ void cross_vo_body(SharedTile& sm, const CrossP& P, int lbid) {
    int tiles = P.tiles;
    int split = lbid / (8 * tiles);
    int rem = lbid - split * 8 * tiles;
    int b = rem / tiles;
    int i0 = (rem - b * tiles) * IT;
    int NVl = P.iN, NOl = P.jN;
    int j_begin = split * P.tps * JT;
    if (j_begin >= NOl) return;
    int j_end = j_begin + P.tps * JT;
    if (j_end > NOl) j_end = NOl;
    int T = (j_end - j_begin + JT - 1) / JT;
    int t = threadIdx.x;
    int rg = t >> 4, c0 = (t & 15) * 4;
    int il = t & 63, jlb = t >> 6;
    float acc[4][8];
#pragma unroll
    for (int q = 0; q < 4; ++q)
#pragma unroll
        for (int x = 0; x < 8; ++x) acc[q][x] = 0.f;
    const float* Ab = P.A + (size_t)b * NOl * NVl;
    const float* srcb = P.src + (size_t)b * NOl * HD;
    int v = i0 + il;
    float w8[8];
    stage_tile_async(srcb + (size_t)j_begin * HD, &sm.hs[0][0][0], t);
#pragma unroll
    for (int k = 0; k < 8; ++k) {
        int o = j_begin + jlb + k * 4;
        w8[k] = (v < NVl && o < NOl) ? Ab[(size_t)o * NVl + v] : 0.f;
    }
    for (int tt = 0; tt < T; ++tt) {
        int cur = tt & 1;
#pragma unroll
        for (int k = 0; k < 8; ++k) sm.ws[cur][jlb + k * 4][il] = w8[k];
        __syncthreads();
        if (tt + 1 < T) {
            int jn = j_begin + (tt + 1) * JT;
            stage_tile_async(srcb + (size_t)jn * HD, &sm.hs[1 - cur][0][0], t);
#pragma unroll
            for (int k = 0; k < 8; ++k) {
                int o = jn + jlb + k * 4;
                w8[k] = (v < NVl && o < NOl) ? Ab[(size_t)o * NVl + v] : 0.f;
            }
        }
        tile_fma256(sm.hs[cur], sm.ws[cur], rg, c0, acc);
    }
    size_t rowsTot = (size_t)8 * NVl;
    part_store256(P.pp, ((size_t)split * rowsTot + (size_t)b * NVl) * HD, i0, NVl, rg, c0, acc);
}

__device__ void cross_ov_body(SharedTile& sm, const CrossP& P, int lbid) {
    int tiles = P.tiles;
    int split = lbid / (8 * tiles);
    int rem = lbid - split * 8 * tiles;
    int b = rem / tiles;
    int i0 = (rem - b * tiles) * IT;
    int NOl = P.iN, NVl = P.jN;
    int j_begin = split * P.tps * JT;
    if (j_begin >= NVl) return;
    int j_end = j_begin + P.tps * JT;
    if (j_end > NVl) j_end = NVl;
    int T = (j_end - j_begin + JT - 1) / JT;
    int t = threadIdx.x;
    int rg = t >> 4, c0 = (t & 15) * 4;
    int il = t >> 2, j4 = (t & 3) * 4;
    float acc[4][8];
#pragma unroll
    for (int q = 0; q < 4; ++q)
#pragma unroll
        for (int x = 0; x < 8; ++x) acc[q][x] = 0.f;
    const float* Ab = P.A + (size_t)b * NOl * NVl;
    const float* srcb = P.src + (size_t)b * NVl * HD;
    const float* r1b = P.rs1 + (size_t)b * NVl;
    int orow = i0 + il;
    float4 a4[2], r4[2];
    stage_tile_async(srcb + (size_t)j_begin * HD, &sm.hs[0][0][0], t);
#pragma unroll
    for (int k = 0; k < 2; ++k) {
        int vv = j_begin + j4 + k * 16;
        float4 av = make_float4(0.f,0.f,0.f,0.f), rv = make_float4(0.f,0.f,0.f,0.f);
        if (orow < NOl) {
            if (vv + 3 < NVl) {
                av = *(const float4*)&Ab[(size_t)orow * NVl + vv];
                rv = *(const float4*)&r1b[vv];
            } else {
                float* ap = (float*)&av; float* rp = (float*)&rv;
                for (int r = 0; r < 4; ++r)
                    if (vv + r < NVl) { ap[r] = Ab[(size_t)orow * NVl + vv + r]; rp[r] = r1b[vv + r]; }
            }
        }
        a4[k] = av; r4[k] = rv;
    }
    for (int tt = 0; tt < T; ++tt) {
        int cur = tt & 1;
#pragma unroll
        for (int k = 0; k < 2; ++k) {
            float wv[4] = {a4[k].x * r4[k].x, a4[k].y * r4[k].y,
                           a4[k].z * r4[k].z, a4[k].w * r4[k].w};
#pragma unroll
            for (int r = 0; r < 4; ++r) sm.ws[cur][j4 + r + k * 16][il] = wv[r];
        }
        __syncthreads();
        if (tt + 1 < T) {
            int jn = j_begin + (tt + 1) * JT;
            stage_tile_async(srcb + (size_t)jn * HD, &sm.hs[1 - cur][0][0], t);
#pragma unroll
            for (int k = 0; k < 2; ++k) {
                int vv = jn + j4 + k * 16;
                float4 av = make_float4(0.f,0.f,0.f,0.f), rv = make_float4(0.f,0.f,0.f,0.f);
                if (orow < NOl) {
                    if (vv + 3 < NVl) {
                        av = *(const float4*)&Ab[(size_t)orow * NVl + vv];
                        rv = *(const float4*)&r1b[vv];
                    } else {
                        float* ap = (float*)&av; float* rp = (float*)&rv;
                        for (int r = 0; r < 4; ++r)
                            if (vv + r < NVl) { ap[r] = Ab[(size_t)orow * NVl + vv + r]; rp[r] = r1b[vv + r]; }
                    }
                }
                a4[k] = av; r4[k] = rv;
            }
        }
        tile_fma256(sm.hs[cur], sm.ws[cur], rg, c0, acc);
    }
    size_t rowsTot = (size_t)8 * NOl;
    part_store256(P.pp, ((size_t)split * rowsTot + (size_t)b * NOl) * HD, i0, NOl, rg, c0, acc);
}

__global__ __launch_bounds__(256)
void cross2_k(CrossP VO, CrossP OV, int GVOb) {
    __shared__ SharedTile sm;
    int bid = blockIdx.x;
    if (bid < GVOb) cross_vo_body(sm, VO, bid);
    else            cross_ov_body(sm, OV, bid - GVOb);
}

// ---------------- fused finalize GAT: sum S partials, /Z, relu ----------------
__global__ __launch_bounds__(256)
void fin2_k(FinP V, FinP O, int GVb) {
    int bid = blockIdx.x;
    const FinP& P = (bid < GVb) ? V : O;
    int idx = ((bid < GVb) ? bid : bid - GVb) * 256 + threadIdx.x;
    int rows = P.rows;
    int row = idx >> 5;
    if (row >= rows) return;
    float4 v = make_float4(0.f, 0.f, 0.f, 0.f);
    for (int s = 0; s < P.S; ++s) {
        float4 p = ((const float4*)P.pp)[((size_t)s * rows + row) * 32 + (idx & 31)];
        v.x += p.x; v.y += p.y; v.z += p.z; v.w += p.w;
    }
    float z = 0.f;
    for (int s = 0; s < P.S; ++s) z += P.zp[(size_t)s * rows + row];
    float sc = 1.f / z;
    v.x = fmaxf(v.x * sc, 0.f); v.y = fmaxf(v.y * sc, 0.f);
    v.z = fmaxf(v.z * sc, 0.f); v.w = fmaxf(v.w * sc, 0.f);
    ((float4*)P.out)[idx] = v;
}

// ---------------- fused MLP: out = (relu(x@W1+b1))@W2 + b2 + res ----------------
__global__ __launch_bounds__(128)
void mlp2_k(MlpP V, MlpP O, int GVb) {
    __shared__ float xs[8][HD];
    __shared__ float hh[8][HD];
    int bid = blockIdx.x;
    const MlpP& P = (bid < GVb) ? V : O;
    int row0 = ((bid < GVb) ? bid : bid - GVb) * 8;
    int rows = P.rows;
    int t = threadIdx.x;
    for (int l = t; l < 8 * 32; l += 128) {
        int r = l >> 5, c4 = l & 31;
        int row = row0 + r;
        float4 v = make_float4(0.f, 0.f, 0.f, 0.f);
        if (row < rows) {
            for (int s = 0; s < P.S; ++s) {
                float4 p = ((const float4*)P.pp)[((size_t)s * rows + row) * 32 + c4];
                v.x += p.x; v.y += p.y; v.z += p.z; v.w += p.w;
            }
            float sc = P.scale[row];
            v.x *= sc; v.y *= sc; v.z *= sc; v.w *= sc;
        }
        ((float4*)&xs[r][0])[c4] = v;
    }
    __syncthreads();
    int wv = t >> 6, tt = t & 63, rb = wv * 4;
    float a0[4] = {0.f, 0.f, 0.f, 0.f}, a1v[4] = {0.f, 0.f, 0.f, 0.f};
#pragma unroll 4
    for (int k = 0; k < HD; ++k) {
        float w0 = P.W1[(size_t)k * HD + tt];
        float w1 = P.W1[(size_t)k * HD + tt + 64];
#pragma unroll
        for (int r = 0; r < 4; ++r) {
            float x = xs[rb + r][k];
            a0[r] = fmaf(x, w0, a0[r]);
            a1v[r] = fmaf(x, w1, a1v[r]);
        }
    }
    float bb0 = P.b1[tt], bb1 = P.b1[tt + 64];
#pragma unroll
    for (int r = 0; r < 4; ++r) {
        hh[rb + r][tt]      = fmaxf(a0[r] + bb0, 0.f);
        hh[rb + r][tt + 64] = fmaxf(a1v[r] + bb1, 0.f);
    }
    __syncthreads();
    float c0a[4] = {0.f, 0.f, 0.f, 0.f}, c1a[4] = {0.f, 0.f, 0.f, 0.f};
#pragma unroll 4
    for (int k = 0; k < HD; ++k) {
        float w0 = P.W2[(size_t)k * HD + tt];
        float w1 = P.W2[(size_t)k * HD + tt + 64];
#pragma unroll
        for (int r = 0; r < 4; ++r) {
            float x = hh[rb + r][k];
            c0a[r] = fmaf(x, w0, c0a[r]);
            c1a[r] = fmaf(x, w1, c1a[r]);
        }
    }
    float d0 = P.b2[tt], d1 = P.b2[tt + 64];
#pragma unroll
    for (int r = 0; r < 4; ++r) {
        int row = row0 + rb + r;
        if (row >= rows) continue;
        P.out[(size_t)row * HD + tt]      = c0a[r] + d0 + P.res[(size_t)row * HD + tt];
        P.out[(size_t)row * HD + tt + 64] = c1a[r] + d1 + P.res[(size_t)row * HD + tt + 64];
    }
}

// ---------------- output projection ----------------
template<int RELU, int BIAS, int RES>
__global__ __launch_bounds__(128)
void linear_k(const float* __restrict__ X, const float* __restrict__ W,
              const float* __restrict__ bias, const float* __restrict__ res,
              float* __restrict__ out, int rows, int K, int Dout) {
    __shared__ float xs[4][512];
    int row0 = blockIdx.x * 4;
    int t = threadIdx.x;
    int K4 = K >> 2;
    for (int l = t; l < 4 * K4; l += 128) {
        int r = l / K4, c4 = l - r * K4;
        float4 val = make_float4(0.f, 0.f, 0.f, 0.f);
        if (row0 + r < rows) val = ((const float4*)(X + (size_t)(row0 + r) * K))[c4];
        ((float4*)&xs[r][0])[c4] = val;
    }
    __syncthreads();
    int chunk = Dout < 256 ? Dout : 256;
    int half = chunk >> 1;
    if (t >= half) return;
    int c0 = blockIdx.y * chunk + t;
    int c1 = c0 + half;
    float a00 = 0, a01 = 0, a02 = 0, a03 = 0, a10 = 0, a11 = 0, a12 = 0, a13 = 0;
#pragma unroll 4
    for (int k = 0; k < K; ++k) {
        float w0 = W[(size_t)k * Dout + c0];
        float w1 = W[(size_t)k * Dout + c1];
        float x0 = xs[0][k], x1 = xs[1][k], x2 = xs[2][k], x3 = xs[3][k];
        a00 = fmaf(x0, w0, a00); a01 = fmaf(x1, w0, a01);
        a02 = fmaf(x2, w0, a02); a03 = fmaf(x3, w0, a03);
        a10 = fmaf(x0, w1, a10); a11 = fmaf(x1, w1, a11);
        a12 = fmaf(x2, w1, a12); a13 = fmaf(x3, w1, a13);
    }
    float accs[2][4] = {{a00, a01, a02, a03}, {a10, a11, a12, a13}};
    int cs[2] = {c0, c1};
    for (int h = 0; h < 2; ++h) {
        float bv = BIAS ? bias[cs[h]] : 0.f;
        for (int r = 0; r < 4; ++r) {
            int row = row0 + r;
            if (row >= rows) continue;
            float v = accs[h][r] + bv;
            if (RES) v += res[(size_t)row * Dout + cs[h]];
            if (RELU) v = fmaxf(v, 0.f);
            out[(size_t)row * Dout + cs[h]] = v;
        }
    }
}

// ---------------- host launcher ----------------
extern "C" void kernel_launch(void* const* d_in, const int* in_sizes, int n_in,
                              void* d_out, int out_size, void* d_ws, size_t ws_size,
                              hipStream_t stream) {
    const int B = 8, NV = 500, NO = 1500, DV = 512, DO = 32;
    const float* vis_memory = (const float*)d_in[0];
    const float* obj_memory = (const float*)d_in[1];
    const float* vis_adj    = (const float*)d_in[2];
    const float* obj_adj    = (const float*)d_in[3];
    const float* A_OV       = (const float*)d_in[4];
    const float* Wv1  = (const float*)d_in[5];
    const float* av1a = (const float*)d_in[6];
    const float* av1b = (const float*)d_in[7];
    const float* Wv2  = (const float*)d_in[8];
    const float* av2a = (const float*)d_in[9];
    const float* av2b = (const float*)d_in[10];
    const float* Wo1  = (const float*)d_in[11];
    const float* ao1a = (const float*)d_in[12];
    const float* ao1b = (const float*)d_in[13];
    const float* Wo2  = (const float*)d_in[14];
    const float* ao2a = (const float*)d_in[15];
    const float* ao2b = (const float*)d_in[16];
    const float* g2o_W1 = (const float*)d_in[17];
    const float* g2o_b1 = (const float*)d_in[18];
    const float* g2o_W2 = (const float*)d_in[19];
    const float* g2o_b2 = (const float*)d_in[20];
    const float* o2g_W1 = (const float*)d_in[21];
    const float* o2g_b1 = (const float*)d_in[22];
    const float* o2g_W2 = (const float*)d_in[23];
    const float* o2g_b2 = (const float*)d_in[24];
    const float* img_W = (const float*)d_in[25];
    const float* img_b = (const float*)d_in[26];
    const float* obj_W = (const float*)d_in[27];
    const float* obj_b = (const float*)d_in[28];

    const int tilesJV = 16, tilesJO = 47;            // ceil(N/32)

    float* wsp = (float*)d_ws;
    size_t off = 0;
    auto alloc = [&](size_t n) { float* p = wsp + off; off += (n + 3) & ~(size_t)3; return p; };
    float* rs1   = alloc(B * NV);
    float* rs2   = alloc(B * NO);
    float* saV   = alloc(B * NV);
    float* sbV   = alloc(B * NV);
    float* smV   = alloc(B);
    float* saO   = alloc(B * NO);
    float* sbO   = alloc(B * NO);
    float* smO   = alloc(B);
    float* s1p   = alloc((size_t)B * CCH * NV);
    // weight-prep outputs (bf16 transposed W + score vectors)
    unsigned short* WTv1 = (unsigned short*)alloc(128 * 512 / 2);
    unsigned short* WTo1 = (unsigned short*)alloc(128 * 32 / 2);
    unsigned short* WTv2 = (unsigned short*)alloc(128 * 128 / 2);
    unsigned short* WTo2 = (unsigned short*)alloc(128 * 128 / 2);
    float* wav1a = alloc(512); float* wav1b = alloc(512);
    float* wao1a = alloc(32);  float* wao1b = alloc(32);
    float* wav2a = alloc(128); float* wav2b = alloc(128);
    float* wao2a = alloc(128); float* wao2b = alloc(128);
    // bf16 X buffers (max over layers: vis 4000x512, obj 12000x128)
    unsigned short* XbfV = (unsigned short*)alloc((size_t)B * NV * 512 / 2);
    unsigned short* XbfO = (unsigned short*)alloc((size_t)B * NO * 128 / 2);
    unsigned short* hTv = (unsigned short*)alloc((size_t)B * tilesJV * 4096 / 2);
    unsigned short* hTo = (unsigned short*)alloc((size_t)B * tilesJO * 4096 / 2);
    float* v1    = alloc((size_t)B * NV * HD);
    float* o1    = alloc((size_t)B * NO * HD);
    float* visb  = alloc((size_t)B * NV * HD);
    float* objb  = alloc((size_t)B * NO * HD);
    float* ppV   = alloc((size_t)8 * B * NV * HD);
    float* zpV   = alloc((size_t)8 * B * NV);
    float* ppO   = alloc((size_t)4 * B * NO * HD);
    float* zpO   = alloc((size_t)4 * B * NO);
    alloc(16384);                                    // tail pad for async/OOB reads

    // weight prep (once): 16 + 1 + 4 + 4 = 25 blocks
    {
        WprepP w0{Wv1, av1a, av1b, WTv1, wav1a, wav1b, DV};
        WprepP w1{Wo1, ao1a, ao1b, WTo1, wao1a, wao1b, DO};
        WprepP w2{Wv2, av2a, av2b, WTv2, wav2a, wav2b, HD};
        WprepP w3{Wo2, ao2a, ao2b, WTo2, wao2a, wao2b, HD};
        wprep_k<<<25, 256, 0, stream>>>(w0, w1, w2, w3, 16, 17, 21);
    }

    colsum_part_k<<<dim3((NV + 255) / 256, CCH, B), 256, 0, stream>>>(A_OV, s1p, B, NO, NV);
    colsum_fin_k<<<dim3((B * NV + 255) / 256), 256, 0, stream>>>(s1p, rs1, B, NV);
    rowsum_inv_k<<<dim3((B * NO + 3) / 4), 256, 0, stream>>>(A_OV, rs1, rs2, B, NO, NV);

    // geometry (IT=64, JT=32):
    const int tilesV = 8, tilesO = 24;               // ceil(N/64)
    const int SV = 8, SO = 4, SVO = 8, SOV = 4;
    const int tpsV = 2;    // ceil(16/8)  j-tiles per split (vis GAT)
    const int tpsO = 12;   // ceil(47/4)  j-tiles per split (obj GAT)
    const int tpsVO = 6;   // ceil(ceil(1500/32)/8)
    const int tpsOV = 4;   // ceil(ceil(500/32)/4)
    const int G_AGG_V = B * tilesV * SV;             // 512
    const int G_AGG_O = B * tilesO * SO;             // 768
    const int G_CR_VO = B * tilesV * SVO;            // 512
    const int G_CR_OV = B * tilesO * SOV;            // 768
    const int G_MLP_V = B * NV / 8;                  // 500
    const int G_MLP_O = B * NO / 8;                  // 1500
    const int G_FIN_V = B * NV * 32 / 256;           // 500
    const int G_FIN_O = B * NO * 32 / 256;           // 1500
    const int G_XP_V = B * NV / 4;                   // 1000
    const int G_XP_O = B * NO / 4;                   // 3000
    const int G_GMF_V = B * tilesJV;                 // 128
    const int G_GMF_O = B * tilesJO;                 // 376

    // shared per-layer tail (everything after h/scores are computed)
    auto tail = [&](float* visout, float* objout) {
        sbmax2_k<<<16, 256, 0, stream>>>(sbV, smV, sbO, smO, NV, NO);
        AggP av{vis_adj, saV, sbV, smV, hTv, ppV, zpV, NV, tilesV, tilesJV, tpsV};
        AggP ao{obj_adj, saO, sbO, smO, hTo, ppO, zpO, NO, tilesO, tilesJO, tpsO};
        agg2_k<<<G_AGG_V + G_AGG_O, THR, 0, stream>>>(av, ao, G_AGG_V);
        FinP fv{ppV, zpV, v1, B * NV, SV};
        FinP fo{ppO, zpO, o1, B * NO, SO};
        fin2_k<<<G_FIN_V + G_FIN_O, 256, 0, stream>>>(fv, fo, G_FIN_V);
        CrossP cvo{A_OV, o1, nullptr, ppV, NV, NO, tilesV, tpsVO};
        CrossP cov{A_OV, v1, rs1, ppO, NO, NV, tilesO, tpsOV};
        cross2_k<<<G_CR_VO + G_CR_OV, THR, 0, stream>>>(cvo, cov, G_CR_VO);
        MlpP mv{ppV, rs1, SVO, o2g_W1, o2g_b1, o2g_W2, o2g_b2, v1, visout, B * NV};
        MlpP mo{ppO, rs2, SOV, g2o_W1, g2o_b1, g2o_W2, g2o_b2, o1, objout, B * NO};
        mlp2_k<<<G_MLP_V + G_MLP_O, 128, 0, stream>>>(mv, mo, G_MLP_V);
    };

    // ---- layer 1 (Kv=512, Ko=32) ----
    {
        XprepP xv{vis_memory, XbfV, wav1a, wav1b, saV, sbV, B * NV};
        XprepP xo{obj_memory, XbfO, wao1a, wao1b, saO, sbO, B * NO};
        xprep2_k<512, 32><<<G_XP_V + G_XP_O, 256, 0, stream>>>(xv, xo, G_XP_V);
        GmfP gv{XbfV, WTv1, hTv, NV, tilesJV};
        GmfP go{XbfO, WTo1, hTo, NO, tilesJO};
        gmf2_k<512, 32><<<G_GMF_V + G_GMF_O, 256, 0, stream>>>(gv, go, G_GMF_V);
        tail(visb, objb);
    }
    // ---- layer 2 (Kv=Ko=128) ----
    {
        XprepP xv{visb, XbfV, wav2a, wav2b, saV, sbV, B * NV};
        XprepP xo{objb, XbfO, wao2a, wao2b, saO, sbO, B * NO};
        xprep2_k<128, 128><<<G_XP_V + G_XP_O, 256, 0, stream>>>(xv, xo, G_XP_V);
        GmfP gv{XbfV, WTv2, hTv, NV, tilesJV};
        GmfP go{XbfO, WTo2, hTo, NO, tilesJO};
        gmf2_k<128, 128><<<G_GMF_V + G_GMF_O, 256, 0, stream>>>(gv, go, G_GMF_V);
        tail(visb, objb);
    }

    // output projections
    float* vis_out = (float*)d_out;
    float* obj_out = vis_out + (size_t)B * NV * DV;
    linear_k<0, 1, 0><<<dim3((B * NV + 3) / 4, (DV + 255) / 256), 128, 0, stream>>>(
        visb, img_W, img_b, nullptr, vis_out, B * NV, HD, DV);
    linear_k<0, 1, 0><<<dim3((B * NO + 3) / 4, 1), 128, 0, stream>>>(
        objb, obj_W, obj_b, nullptr, obj_out, B * NO, HD, DO);
}